// Round 3
// baseline (171.098 us; speedup 1.0000x reference)
//
#include <hip/hip_runtime.h>

// z: [32,64,32,32] fp32, codebook: [1024,64] fp32
#define B_DIM   32
#define C_DIM   64
#define K_CODES 1024
#define HW      1024                     // 32*32
#define CHW     (C_DIM * HW)             // 65536
#define N_TOTAL (B_DIM * HW)             // 32768
#define CODES_ELEMS (B_DIM * C_DIM * HW) // 2097152

#define KPARTS 16                        // waves per block == k partitions
#define NPB    64                        // n's per block (lanes)
#define KP_LEN (K_CODES / KPARTS)        // 64 k's per wave
#define KGROUP 4                         // independent k-chains (ILP)

__launch_bounds__(NPB * KPARTS, 8)       // 1024 thr; 8 waves/EU -> 2 blocks/CU
__global__ void vq_kernel(const float* __restrict__ z, const float* __restrict__ cb,
                          float* __restrict__ out) {
    const int t  = threadIdx.x;
    const int nl = t & (NPB - 1);
    // wave id == k partition; readfirstlane pins wave-uniformity so codebook
    // row reads lower to s_load (scalar pipe, SGPR-operand FMAs).
    const int part = __builtin_amdgcn_readfirstlane(t >> 6);

    // ---- cnorm[0..1023] into LDS, one row per thread; numpy-pairwise order
    // to match jnp.sum(cb*cb, axis=1) rounding exactly.
    __shared__ float s_cnorm[K_CODES];
    {
        const int k = t;
        const float4* row = (const float4*)(cb + k * C_DIM);
        float v[C_DIM];
#pragma unroll
        for (int q = 0; q < 16; ++q) {
            float4 f = row[q];
            v[4*q+0] = f.x; v[4*q+1] = f.y; v[4*q+2] = f.z; v[4*q+3] = f.w;
        }
        float r[8];
#pragma unroll
        for (int j = 0; j < 8; ++j) r[j] = v[j] * v[j];
#pragma unroll
        for (int i = 8; i < 64; i += 8) {
#pragma unroll
            for (int j = 0; j < 8; ++j) r[j] = fmaf(v[i + j], v[i + j], r[j]);
        }
        s_cnorm[k] = ((r[0] + r[1]) + (r[2] + r[3])) + ((r[4] + r[5]) + (r[6] + r[7]));
    }

    // ---- This thread's x vector: z[b][c][h][w], coalesced across lanes per c.
    const int n  = blockIdx.x * NPB + nl;
    const int b  = n >> 10;
    const int hw = n & (HW - 1);
    const float* zp = z + b * CHW + hw;
    float x[C_DIM];
#pragma unroll
    for (int c = 0; c < C_DIM; ++c) x[c] = zp[c * HW];

    // xnorm, numpy-pairwise
    float xr[8];
#pragma unroll
    for (int j = 0; j < 8; ++j) xr[j] = x[j] * x[j];
#pragma unroll
    for (int i = 8; i < 64; i += 8) {
#pragma unroll
        for (int j = 0; j < 8; ++j) xr[j] = fmaf(x[i + j], x[i + j], xr[j]);
    }
    const float xnorm = ((xr[0] + xr[1]) + (xr[2] + xr[3])) + ((xr[4] + xr[5]) + (xr[6] + xr[7]));

    __syncthreads();   // s_cnorm ready

    // ---- Scan this wave's 64-k partition, KGROUP independent dot chains.
    // Per-dot fp32 accumulation order identical to the serial version
    // (sequential over c) -> same rounding -> same argmin as before.
    float best = 3.4e38f;
    int   bidx = 0;
    const int k0 = part * KP_LEN;
    for (int kg = k0; kg < k0 + KP_LEN; kg += KGROUP) {
        const float* cr[KGROUP];
        float d[KGROUP];
#pragma unroll
        for (int j = 0; j < KGROUP; ++j) { cr[j] = cb + (kg + j) * C_DIM; d[j] = 0.f; }
#pragma unroll
        for (int c = 0; c < C_DIM; ++c) {
#pragma unroll
            for (int j = 0; j < KGROUP; ++j) d[j] = fmaf(x[c], cr[j][c], d[j]);
        }
#pragma unroll
        for (int j = 0; j < KGROUP; ++j) {
            float dist = fmaf(-2.f, d[j], xnorm) + s_cnorm[kg + j];  // ref order
            if (dist < best) { best = dist; bidx = kg + j; }         // strict '<'
        }
    }

    // ---- Cross-partition argmin reduce (ascending p, strict '<' keeps lowest k).
    __shared__ float s_score[KPARTS][NPB];
    __shared__ int   s_idx[KPARTS][NPB];
    __shared__ int   s_best[NPB];
    s_score[part][nl] = best;
    s_idx[part][nl]   = bidx;
    __syncthreads();
    if (part == 0) {
        float bb = s_score[0][nl];
        int   bi = s_idx[0][nl];
#pragma unroll
        for (int p = 1; p < KPARTS; ++p) {
            float sc = s_score[p][nl];
            if (sc < bb) { bb = sc; bi = s_idx[p][nl]; }
        }
        s_best[nl] = bi;
        out[CODES_ELEMS + n] = (float)bi;   // indices (fp32 in out buffer)
    }
    __syncthreads();

    // ---- Codes: out[b][c][h][w] = cb[idx][c]; 4 c's per partition, coalesced.
    const int idx = s_best[nl];
    const float* sel = cb + idx * C_DIM;
    float* op = out + b * CHW + hw;
#pragma unroll
    for (int i = 0; i < 4; ++i) {
        const int c = part * 4 + i;
        op[c * HW] = sel[c];
    }
}

extern "C" void kernel_launch(void* const* d_in, const int* in_sizes, int n_in,
                              void* d_out, int out_size, void* d_ws, size_t ws_size,
                              hipStream_t stream) {
    const float* z  = (const float*)d_in[0];
    const float* cb = (const float*)d_in[1];
    float* out = (float*)d_out;
    vq_kernel<<<N_TOTAL / NPB, NPB * KPARTS, 0, stream>>>(z, cb, out);
}

// Round 4
// 148.953 us; speedup vs baseline: 1.1487x; 1.1487x over previous
//
#include <hip/hip_runtime.h>

// z: [32,64,32,32] fp32, codebook: [1024,64] fp32
#define B_DIM   32
#define C_DIM   64
#define K_CODES 1024
#define HW      1024                     // 32*32
#define CHW     (C_DIM * HW)             // 65536
#define N_TOTAL (B_DIM * HW)             // 32768
#define CODES_ELEMS (B_DIM * C_DIM * HW) // 2097152

#define KPARTS 8                         // waves per block == k partitions
#define NPB    64                        // n's per block (lanes)
#define KP_LEN (K_CODES / KPARTS)        // 128 k's per wave
#define KGROUP 4                         // independent k-chains (ILP)

// (512, 4): min 4 waves/EU -> VGPR cap 128. This tells the backend to target
// 4 waves/EU occupancy instead of its default ~10, so x[64] stays register-
// resident instead of being rematerialized from global in the k-loop
// (R2: VGPR=48 + VALUBusy 64% = remat; R3: VGPR=32 + 61MB scratch = spill).
__launch_bounds__(NPB * KPARTS, 4)
__global__ void vq_kernel(const float* __restrict__ z, const float* __restrict__ cb,
                          float* __restrict__ out) {
    const int t  = threadIdx.x;
    const int nl = t & (NPB - 1);
    // wave id == k partition; readfirstlane pins wave-uniformity so codebook
    // row reads lower to s_load (scalar pipe, SGPR-operand FMAs).
    const int part = __builtin_amdgcn_readfirstlane(t >> 6);

    // ---- cnorm[0..1023] into LDS (2 rows per thread), numpy-pairwise order.
    __shared__ float s_cnorm[K_CODES];
#pragma unroll
    for (int rep = 0; rep < 2; ++rep) {
        const int k = t + rep * 512;
        const float4* row = (const float4*)(cb + k * C_DIM);
        float v[C_DIM];
#pragma unroll
        for (int q = 0; q < 16; ++q) {
            float4 f = row[q];
            v[4*q+0] = f.x; v[4*q+1] = f.y; v[4*q+2] = f.z; v[4*q+3] = f.w;
        }
        float r[8];
#pragma unroll
        for (int j = 0; j < 8; ++j) r[j] = v[j] * v[j];
#pragma unroll
        for (int i = 8; i < 64; i += 8) {
#pragma unroll
            for (int j = 0; j < 8; ++j) r[j] = fmaf(v[i + j], v[i + j], r[j]);
        }
        s_cnorm[k] = ((r[0] + r[1]) + (r[2] + r[3])) + ((r[4] + r[5]) + (r[6] + r[7]));
    }

    // ---- This thread's x vector: z[b][c][h][w], coalesced across lanes per c.
    const int n  = blockIdx.x * NPB + nl;
    const int b  = n >> 10;
    const int hw = n & (HW - 1);
    const float* zp = z + b * CHW + hw;
    float x[C_DIM];
#pragma unroll
    for (int c = 0; c < C_DIM; ++c) x[c] = zp[c * HW];

    // xnorm, numpy-pairwise
    float xr[8];
#pragma unroll
    for (int j = 0; j < 8; ++j) xr[j] = x[j] * x[j];
#pragma unroll
    for (int i = 8; i < 64; i += 8) {
#pragma unroll
        for (int j = 0; j < 8; ++j) xr[j] = fmaf(x[i + j], x[i + j], xr[j]);
    }
    const float xnorm = ((xr[0] + xr[1]) + (xr[2] + xr[3])) + ((xr[4] + xr[5]) + (xr[6] + xr[7]));

    // Pin x[] into VGPRs: empty asm with "+v" makes each element a live,
    // non-rematerializable register value for the whole k-loop.
#pragma unroll
    for (int c = 0; c < C_DIM; ++c) asm volatile("" : "+v"(x[c]));

    __syncthreads();   // s_cnorm ready

    // ---- Scan this wave's 128-k partition, KGROUP independent dot chains.
    float best = 3.4e38f;
    int   bidx = 0;
    const int k0 = part * KP_LEN;
    for (int kg = k0; kg < k0 + KP_LEN; kg += KGROUP) {
        const float* cr[KGROUP];
        float d[KGROUP];
#pragma unroll
        for (int j = 0; j < KGROUP; ++j) { cr[j] = cb + (kg + j) * C_DIM; d[j] = 0.f; }
#pragma unroll
        for (int c = 0; c < C_DIM; ++c) {
#pragma unroll
            for (int j = 0; j < KGROUP; ++j) d[j] = fmaf(x[c], cr[j][c], d[j]);
        }
#pragma unroll
        for (int j = 0; j < KGROUP; ++j) {
            float dist = fmaf(-2.f, d[j], xnorm) + s_cnorm[kg + j];  // ref order
            if (dist < best) { best = dist; bidx = kg + j; }         // strict '<'
        }
    }

    // ---- Cross-partition argmin reduce (ascending p, strict '<' keeps lowest k).
    __shared__ float s_score[KPARTS][NPB];
    __shared__ int   s_idx[KPARTS][NPB];
    __shared__ int   s_best[NPB];
    s_score[part][nl] = best;
    s_idx[part][nl]   = bidx;
    __syncthreads();
    if (part == 0) {
        float bb = s_score[0][nl];
        int   bi = s_idx[0][nl];
#pragma unroll
        for (int p = 1; p < KPARTS; ++p) {
            float sc = s_score[p][nl];
            if (sc < bb) { bb = sc; bi = s_idx[p][nl]; }
        }
        s_best[nl] = bi;
        out[CODES_ELEMS + n] = (float)bi;   // indices (fp32 in out buffer)
    }
    __syncthreads();

    // ---- Codes: out[b][c][h][w] = cb[idx][c]; 8 c's per partition, coalesced.
    const int idx = s_best[nl];
    const float* sel = cb + idx * C_DIM;
    float* op = out + b * CHW + hw;
#pragma unroll
    for (int i = 0; i < 8; ++i) {
        const int c = part * 8 + i;
        op[c * HW] = sel[c];
    }
}

extern "C" void kernel_launch(void* const* d_in, const int* in_sizes, int n_in,
                              void* d_out, int out_size, void* d_ws, size_t ws_size,
                              hipStream_t stream) {
    const float* z  = (const float*)d_in[0];
    const float* cb = (const float*)d_in[1];
    float* out = (float*)d_out;
    vq_kernel<<<N_TOTAL / NPB, NPB * KPARTS, 0, stream>>>(z, cb, out);
}

// Round 5
// 105.191 us; speedup vs baseline: 1.6265x; 1.4160x over previous
//
#include <hip/hip_runtime.h>

// z: [32,64,32,32] fp32, codebook: [1024,64] fp32
#define C_DIM   64
#define K_CODES 1024
#define HW      1024
#define CHW     (C_DIM * HW)             // 65536
#define N_TOTAL 32768
#define CODES_ELEMS 2097152

#define THREADS 512                      // 8 waves: wave w -> ktl = w&3 (k-split), nt = w>>2 (n-tile)
#define NBLK    64                       // n's per block (2 n-tiles of 32)
#define NGROUPS 8                        // k groups of 128 (4 k-tiles of 32)

typedef _Float16 half8  __attribute__((ext_vector_type(8)));
typedef float    f32x16 __attribute__((ext_vector_type(16)));

// (k1,i1) better than (k2,i2) for argmax-with-lowest-index-tiebreak
__device__ __forceinline__ bool better(float k1, int i1, float k2, int i2) {
    return (k1 > k2) || (k1 == k2 && i1 < i2);
}
// merge (bk,bi,sk,si) with other top-2 (obk,obi,osk,osi)
__device__ __forceinline__ void merge2(float& bk, int& bi, float& sk, int& si,
                                       float obk, int obi, float osk, int osi) {
    if (better(obk, obi, bk, bi)) {
        // other's best wins; second = better of (my best, other's second)
        float nsk; int nsi;
        if (better(bk, bi, osk, osi)) { nsk = bk; nsi = bi; } else { nsk = osk; nsi = osi; }
        bk = obk; bi = obi; sk = nsk; si = nsi;
    } else {
        if (better(obk, obi, sk, si)) { sk = obk; si = obi; }
    }
}

__launch_bounds__(THREADS, 4)
__global__ void vq_kernel(const float* __restrict__ z, const float* __restrict__ cb,
                          float* __restrict__ out) {
    // LDS: staging region (B-frags first, then per-group A-frags), cnorm, reduce scratch
    __shared__ half8 sStage[2048];                 // 32 KB
    __shared__ float sCnorm[K_CODES];              // 4 KB
    __shared__ float sRed[2][4][32][4];            // [nt][ktl][col][bk,bi,sk,si] 4 KB
    __shared__ int   sIdxF[NBLK];

    const int t    = threadIdx.x;
    const int lane = t & 63;
    const int w    = t >> 6;          // wave 0..7
    const int ktl  = w & 3;           // k-tile split within group
    const int nt   = w >> 2;          // n-tile (0..1)
    const int base_n = blockIdx.x * NBLK;

    // ---- Phase 1a: cnorm (any order; feeds approx key only) ----
    for (int rep = 0; rep < 2; ++rep) {
        const int kk = t + rep * 512;
        const float4* row = (const float4*)(cb + kk * C_DIM);
        float r[8];
        {
            float4 f0 = row[0], f1 = row[1];
            float v[8] = {f0.x,f0.y,f0.z,f0.w,f1.x,f1.y,f1.z,f1.w};
#pragma unroll
            for (int j = 0; j < 8; ++j) r[j] = v[j]*v[j];
        }
#pragma unroll
        for (int i = 2; i < 16; i += 2) {
            float4 f0 = row[i], f1 = row[i+1];
            float v[8] = {f0.x,f0.y,f0.z,f0.w,f1.x,f1.y,f1.z,f1.w};
#pragma unroll
            for (int j = 0; j < 8; ++j) r[j] = fmaf(v[j], v[j], r[j]);
        }
        sCnorm[kk] = ((r[0]+r[1])+(r[2]+r[3])) + ((r[4]+r[5])+(r[6]+r[7]));
    }

    // ---- Phase 1b: stage B-fragments (x split to fp16 hi/lo) into sStage[0..1024) ----
    {
        // frag row id = t: nt_s = t>>8, q = (t>>6)&3, l = t&63
        const int nt_s = t >> 8, q = (t >> 6) & 3, l = t & 63;
        const int gg = l >> 5;
        const int n_g = base_n + nt_s * 32 + (l & 31);
        const int bb = n_g >> 10, hwv = n_g & 1023;
        const int c0 = q * 16 + gg * 8;
        half8 h8, l8;
#pragma unroll
        for (int j = 0; j < 8; ++j) {
            float v = z[bb * CHW + (c0 + j) * HW + hwv];
            _Float16 hh = (_Float16)v;
            _Float16 ll = (_Float16)(v - (float)hh);
            h8[j] = hh; l8[j] = ll;
        }
        sStage[((nt_s * 4 + q) * 2 + 0) * 64 + l] = h8;
        sStage[((nt_s * 4 + q) * 2 + 1) * 64 + l] = l8;
    }
    __syncthreads();

    // ---- Phase 2: each wave loads its n-tile's B-frags into registers ----
    half8 b_xh[4], b_xl[4];
#pragma unroll
    for (int q = 0; q < 4; ++q) {
        b_xh[q] = sStage[((nt * 4 + q) * 2 + 0) * 64 + lane];
        b_xl[q] = sStage[((nt * 4 + q) * 2 + 1) * 64 + lane];
    }
    // ones-frag for the cnorm-fold chunk (B[k=0]=B[k=1]=1)
    half8 b_one = {};
    if (lane < 32) { b_one[0] = (_Float16)1.0f; b_one[1] = (_Float16)1.0f; }
    __syncthreads();   // B copied out; sStage free for A staging

    // ---- Phase 3: k-group loop ----
    float bk = -3.4e38f, sk = -3.4e38f;
    int   bi = 0,        si = 0;

    for (int g = 0; g < NGROUPS; ++g) {
        // stage group's codebook fragments: 1024 frag-rows, 2 per thread
#pragma unroll
        for (int rep = 0; rep < 2; ++rep) {
            const int rid = t + rep * 512;
            const int kt_s = rid >> 8, q = (rid >> 6) & 3, l = rid & 63;
            const int gg = l >> 5;
            const int kg = g * 128 + kt_s * 32 + (l & 31);
            const int c0 = q * 16 + gg * 8;
            const float4* p = (const float4*)(cb + kg * C_DIM + c0);
            float4 f0 = p[0], f1 = p[1];
            float v[8] = {f0.x,f0.y,f0.z,f0.w,f1.x,f1.y,f1.z,f1.w};
            half8 h8, l8;
#pragma unroll
            for (int j = 0; j < 8; ++j) {
                _Float16 hh = (_Float16)v[j];
                _Float16 ll = (_Float16)(v[j] - (float)hh);
                h8[j] = hh; l8[j] = ll;
            }
            sStage[((kt_s * 4 + q) * 2 + 0) * 64 + l] = h8;
            sStage[((kt_s * 4 + q) * 2 + 1) * 64 + l] = l8;
        }
        __syncthreads();

        // read A-frags for this wave's k-tile
        half8 a_h[4], a_l[4];
#pragma unroll
        for (int q = 0; q < 4; ++q) {
            a_h[q] = sStage[((ktl * 4 + q) * 2 + 0) * 64 + lane];
            a_l[q] = sStage[((ktl * 4 + q) * 2 + 1) * 64 + lane];
        }
        // cnorm-fold A chunk: row m holds [-cn/2 hi, -cn/2 lo, 0...] in k-slots 0,1
        half8 a_cn = {};
        {
            float cn = sCnorm[g * 128 + ktl * 32 + (lane & 31)];
            float cn2 = -0.5f * cn;
            _Float16 hh = (_Float16)cn2;
            _Float16 ll = (_Float16)(cn2 - (float)hh);
            if (lane < 32) { a_cn[0] = hh; a_cn[1] = ll; }
        }

        // MFMA: key = (xh+xl)·(ch+cl) - cn/2, ll term dropped (~2e-7)
        f32x16 acc = {};
#pragma unroll
        for (int q = 0; q < 4; ++q) acc = __builtin_amdgcn_mfma_f32_32x32x16_f16(a_h[q], b_xh[q], acc, 0, 0, 0);
#pragma unroll
        for (int q = 0; q < 4; ++q) acc = __builtin_amdgcn_mfma_f32_32x32x16_f16(a_l[q], b_xh[q], acc, 0, 0, 0);
#pragma unroll
        for (int q = 0; q < 4; ++q) acc = __builtin_amdgcn_mfma_f32_32x32x16_f16(a_h[q], b_xl[q], acc, 0, 0, 0);
        acc = __builtin_amdgcn_mfma_f32_32x32x16_f16(a_cn, b_one, acc, 0, 0, 0);

        // top-2 epilogue; in-lane k strictly ascending -> strict '>' keeps first
        const int kbase = g * 128 + ktl * 32 + 4 * (lane >> 5);
#pragma unroll
        for (int r = 0; r < 16; ++r) {
            float v = acc[r];
            int ki = kbase + (r & 3) + 8 * (r >> 2);
            if (v > bk)      { sk = bk; si = bi; bk = v; bi = ki; }
            else if (v > sk) { sk = v; si = ki; }
        }
        __syncthreads();
    }

    // ---- Phase 4: merge lane halves (same n, complementary k rows) ----
    {
        float obk = __shfl_xor(bk, 32, 64); int obi = __shfl_xor(bi, 32, 64);
        float osk = __shfl_xor(sk, 32, 64); int osi = __shfl_xor(si, 32, 64);
        merge2(bk, bi, sk, si, obk, obi, osk, osi);
    }
    if (lane < 32) {
        sRed[nt][ktl][lane][0] = bk;
        sRed[nt][ktl][lane][1] = __int_as_float(bi);
        sRed[nt][ktl][lane][2] = sk;
        sRed[nt][ktl][lane][3] = __int_as_float(si);
    }
    __syncthreads();

    // ---- Phase 5: per-n final merge + exact fp32 top-2 refinement (t < 64) ----
    if (t < NBLK) {
        const int ntf = t >> 5, col = t & 31;
        float fbk = sRed[ntf][0][col][0]; int fbi = __float_as_int(sRed[ntf][0][col][1]);
        float fsk = sRed[ntf][0][col][2]; int fsi = __float_as_int(sRed[ntf][0][col][3]);
#pragma unroll
        for (int p = 1; p < 4; ++p)
            merge2(fbk, fbi, fsk, fsi,
                   sRed[ntf][p][col][0], __float_as_int(sRed[ntf][p][col][1]),
                   sRed[ntf][p][col][2], __float_as_int(sRed[ntf][p][col][3]));

        // exact fp32 recompute (R1's verified-vs-np recipe) for the two candidates
        const int n_g = base_n + t;
        const int bb = n_g >> 10, hwv = n_g & 1023;
        const float* zp = z + bb * CHW + hwv;
        float x[C_DIM];
#pragma unroll
        for (int c = 0; c < C_DIM; ++c) x[c] = zp[c * HW];
        float xr[8];
#pragma unroll
        for (int j = 0; j < 8; ++j) xr[j] = x[j] * x[j];
#pragma unroll
        for (int i = 8; i < 64; i += 8) {
#pragma unroll
            for (int j = 0; j < 8; ++j) xr[j] = fmaf(x[i+j], x[i+j], xr[j]);
        }
        const float xnorm = ((xr[0]+xr[1])+(xr[2]+xr[3])) + ((xr[4]+xr[5])+(xr[6]+xr[7]));

        float d[2]; int cand[2] = {fbi, fsi};
#pragma unroll
        for (int cidx = 0; cidx < 2; ++cidx) {
            const float* crow = cb + cand[cidx] * C_DIM;
            float dot = 0.f;
#pragma unroll
            for (int c = 0; c < C_DIM; ++c) dot = fmaf(x[c], crow[c], dot);
            float cr[8];
#pragma unroll
            for (int j = 0; j < 8; ++j) cr[j] = crow[j] * crow[j];
#pragma unroll
            for (int i = 8; i < 64; i += 8) {
#pragma unroll
                for (int j = 0; j < 8; ++j) cr[j] = fmaf(crow[i+j], crow[i+j], cr[j]);
            }
            float cn = ((cr[0]+cr[1])+(cr[2]+cr[3])) + ((cr[4]+cr[5])+(cr[6]+cr[7]));
            d[cidx] = fmaf(-2.f, dot, xnorm) + cn;
        }
        int win = (d[1] < d[0] || (d[1] == d[0] && cand[1] < cand[0])) ? cand[1] : cand[0];
        sIdxF[t] = win;
        out[CODES_ELEMS + n_g] = (float)win;
    }
    __syncthreads();

    // ---- Phase 6: write codes, coalesced per c-step ----
    {
        const int c_hi = t >> 6, nl = t & 63;
        const int idx = sIdxF[nl];
        const int n_g = base_n + nl;
        const int bb = n_g >> 10, hwv = n_g & 1023;
#pragma unroll
        for (int j = 0; j < 8; ++j) {
            const int c = c_hi * 8 + j;
            out[bb * CHW + c * HW + hwv] = cb[idx * C_DIM + c];
        }
    }
}

extern "C" void kernel_launch(void* const* d_in, const int* in_sizes, int n_in,
                              void* d_out, int out_size, void* d_ws, size_t ws_size,
                              hipStream_t stream) {
    const float* z  = (const float*)d_in[0];
    const float* cb = (const float*)d_in[1];
    float* out = (float*)d_out;
    vq_kernel<<<N_TOTAL / NBLK, THREADS, 0, stream>>>(z, cb, out);
}

// Round 6
// 91.982 us; speedup vs baseline: 1.8601x; 1.1436x over previous
//
#include <hip/hip_runtime.h>

// z: [32,64,32,32] fp32, codebook: [1024,64] fp32
#define C_DIM   64
#define K_CODES 1024
#define HW      1024
#define CHW     (C_DIM * HW)             // 65536
#define N_TOTAL 32768
#define CODES_ELEMS 2097152

#define THREADS 512                      // 8 waves: wave w -> ktl = w&3 (k-split), nt = w>>2 (n-tile)
#define NBLK    64                       // n's per block (2 n-tiles of 32)
#define NGROUPS 8                        // k groups of 128 (4 k-tiles of 32 each)

typedef _Float16 half8  __attribute__((ext_vector_type(8)));
typedef float    f32x16 __attribute__((ext_vector_type(16)));

// ws layout: [0, 256KB) A-frags (half8[16384]); [256KB, 260KB) cnorm (float[1024])
#define WS_A_ELEMS 16384
#define WS_CN_OFF  WS_A_ELEMS            // in half8 units; cast at use site

__device__ __forceinline__ bool better(float k1, int i1, float k2, int i2) {
    return (k1 > k2) || (k1 == k2 && i1 < i2);
}
__device__ __forceinline__ void merge2(float& bk, int& bi, float& sk, int& si,
                                       float obk, int obi, float osk, int osi) {
    if (better(obk, obi, bk, bi)) {
        float nsk; int nsi;
        if (better(bk, bi, osk, osi)) { nsk = bk; nsi = bi; } else { nsk = osk; nsi = osi; }
        bk = obk; bi = obi; sk = nsk; si = nsi;
    } else {
        if (better(obk, obi, sk, si)) { sk = obk; si = obi; }
    }
}

// One-shot prep: blocks 0..31 convert codebook -> hi/lo fp16 A-fragment layout;
// block 32 computes exact np-pairwise cnorm[1024].
__global__ void prep_kernel(const float* __restrict__ cb, half8* __restrict__ wsA,
                            float* __restrict__ wsCn) {
    if (blockIdx.x < 32) {
        const int tid = blockIdx.x * 256 + threadIdx.x;   // 0..8191
        const int kt = tid >> 8, q = (tid >> 6) & 3, l = tid & 63;
        const int k  = kt * 32 + (l & 31);
        const int c0 = q * 16 + (l >> 5) * 8;
        const float4* p = (const float4*)(cb + k * C_DIM + c0);
        float4 f0 = p[0], f1 = p[1];
        float v[8] = {f0.x,f0.y,f0.z,f0.w,f1.x,f1.y,f1.z,f1.w};
        half8 h8, l8;
#pragma unroll
        for (int j = 0; j < 8; ++j) {
            _Float16 hh = (_Float16)v[j];
            _Float16 ll = (_Float16)(v[j] - (float)hh);
            h8[j] = hh; l8[j] = ll;
        }
        wsA[((kt * 4 + q) * 2 + 0) * 64 + l] = h8;
        wsA[((kt * 4 + q) * 2 + 1) * 64 + l] = l8;
    } else {
        // cnorm: 256 threads x 4 rows, numpy-pairwise (stride-8 accumulators)
#pragma unroll
        for (int rep = 0; rep < 4; ++rep) {
            const int k = threadIdx.x * 4 + rep;
            const float4* row = (const float4*)(cb + k * C_DIM);
            float r[8];
            {
                float4 f0 = row[0], f1 = row[1];
                float v[8] = {f0.x,f0.y,f0.z,f0.w,f1.x,f1.y,f1.z,f1.w};
#pragma unroll
                for (int j = 0; j < 8; ++j) r[j] = v[j]*v[j];
            }
#pragma unroll
            for (int i = 2; i < 16; i += 2) {
                float4 f0 = row[i], f1 = row[i+1];
                float v[8] = {f0.x,f0.y,f0.z,f0.w,f1.x,f1.y,f1.z,f1.w};
#pragma unroll
                for (int j = 0; j < 8; ++j) r[j] = fmaf(v[j], v[j], r[j]);
            }
            wsCn[k] = ((r[0]+r[1])+(r[2]+r[3])) + ((r[4]+r[5])+(r[6]+r[7]));
        }
    }
}

__launch_bounds__(THREADS, 4)
__global__ void vq_kernel(const float* __restrict__ z, const float* __restrict__ cb,
                          const half8* __restrict__ wsA, const float* __restrict__ wsCn,
                          float* __restrict__ out) {
    __shared__ half8 sStage[1024];                 // 16 KB: B-frags only
    __shared__ float sRed[2][4][32][4];            // [nt][ktl][col][bk,bi,sk,si]
    __shared__ int   sIdxF[NBLK];

    const int t    = threadIdx.x;
    const int lane = t & 63;
    const int w    = t >> 6;
    const int ktl  = w & 3;
    const int nt   = w >> 2;
    const int base_n = blockIdx.x * NBLK;

    // ---- Stage B-fragments (x split to fp16 hi/lo); 2-transaction/inst reads.
    {
        const int nt_s = t >> 8, q = (t >> 6) & 3, l = t & 63;
        const int n_g = base_n + nt_s * 32 + (l & 31);
        const int bb = n_g >> 10, hwv = n_g & 1023;
        const int c0 = q * 16 + (l >> 5) * 8;
        half8 h8, l8;
#pragma unroll
        for (int j = 0; j < 8; ++j) {
            float v = z[bb * CHW + (c0 + j) * HW + hwv];
            _Float16 hh = (_Float16)v;
            _Float16 ll = (_Float16)(v - (float)hh);
            h8[j] = hh; l8[j] = ll;
        }
        sStage[((nt_s * 4 + q) * 2 + 0) * 64 + l] = h8;
        sStage[((nt_s * 4 + q) * 2 + 1) * 64 + l] = l8;
    }
    __syncthreads();

    half8 b_xh[4], b_xl[4];
#pragma unroll
    for (int q = 0; q < 4; ++q) {
        b_xh[q] = sStage[((nt * 4 + q) * 2 + 0) * 64 + lane];
        b_xl[q] = sStage[((nt * 4 + q) * 2 + 1) * 64 + lane];
    }
    half8 b_one = {};
    if (lane < 32) { b_one[0] = (_Float16)1.0f; b_one[1] = (_Float16)1.0f; }

    // ---- k-group loop: no barriers, no LDS, coalesced frag loads from ws.
    float bk = -3.4e38f, sk = -3.4e38f;
    int   bi = 0,        si = 0;

    for (int g = 0; g < NGROUPS; ++g) {
        const int kt = g * 4 + ktl;                 // global k-tile 0..31
        half8 a_h[4], a_l[4];
#pragma unroll
        for (int q = 0; q < 4; ++q) {
            a_h[q] = wsA[((kt * 4 + q) * 2 + 0) * 64 + lane];
            a_l[q] = wsA[((kt * 4 + q) * 2 + 1) * 64 + lane];
        }
        half8 a_cn = {};
        {
            float cn2 = -0.5f * wsCn[kt * 32 + (lane & 31)];
            _Float16 hh = (_Float16)cn2;
            _Float16 ll = (_Float16)(cn2 - (float)hh);
            if (lane < 32) { a_cn[0] = hh; a_cn[1] = ll; }
        }

        f32x16 acc = {};
#pragma unroll
        for (int q = 0; q < 4; ++q) acc = __builtin_amdgcn_mfma_f32_32x32x16_f16(a_h[q], b_xh[q], acc, 0, 0, 0);
#pragma unroll
        for (int q = 0; q < 4; ++q) acc = __builtin_amdgcn_mfma_f32_32x32x16_f16(a_l[q], b_xh[q], acc, 0, 0, 0);
#pragma unroll
        for (int q = 0; q < 4; ++q) acc = __builtin_amdgcn_mfma_f32_32x32x16_f16(a_h[q], b_xl[q], acc, 0, 0, 0);
        acc = __builtin_amdgcn_mfma_f32_32x32x16_f16(a_cn, b_one, acc, 0, 0, 0);

        const int kbase = kt * 32 + 4 * (lane >> 5);
#pragma unroll
        for (int r = 0; r < 16; ++r) {
            float v = acc[r];
            int ki = kbase + (r & 3) + 8 * (r >> 2);
            if (v > bk)      { sk = bk; si = bi; bk = v; bi = ki; }
            else if (v > sk) { sk = v; si = ki; }
        }
    }

    // ---- merge lane halves (same n, complementary rows)
    {
        float obk = __shfl_xor(bk, 32, 64); int obi = __shfl_xor(bi, 32, 64);
        float osk = __shfl_xor(sk, 32, 64); int osi = __shfl_xor(si, 32, 64);
        merge2(bk, bi, sk, si, obk, obi, osk, osi);
    }
    if (lane < 32) {
        sRed[nt][ktl][lane][0] = bk;
        sRed[nt][ktl][lane][1] = __int_as_float(bi);
        sRed[nt][ktl][lane][2] = sk;
        sRed[nt][ktl][lane][3] = __int_as_float(si);
    }
    __syncthreads();

    // ---- per-n final merge + exact fp32 top-2 refinement (t < 64)
    if (t < NBLK) {
        const int ntf = t >> 5, col = t & 31;
        float fbk = sRed[ntf][0][col][0]; int fbi = __float_as_int(sRed[ntf][0][col][1]);
        float fsk = sRed[ntf][0][col][2]; int fsi = __float_as_int(sRed[ntf][0][col][3]);
#pragma unroll
        for (int p = 1; p < 4; ++p)
            merge2(fbk, fbi, fsk, fsi,
                   sRed[ntf][p][col][0], __float_as_int(sRed[ntf][p][col][1]),
                   sRed[ntf][p][col][2], __float_as_int(sRed[ntf][p][col][3]));

        const int n_g = base_n + t;
        const int bb = n_g >> 10, hwv = n_g & 1023;
        const float* zp = z + bb * CHW + hwv;
        float x[C_DIM];
#pragma unroll
        for (int c = 0; c < C_DIM; ++c) x[c] = zp[c * HW];
        float xr[8];
#pragma unroll
        for (int j = 0; j < 8; ++j) xr[j] = x[j] * x[j];
#pragma unroll
        for (int i = 8; i < 64; i += 8) {
#pragma unroll
            for (int j = 0; j < 8; ++j) xr[j] = fmaf(x[i+j], x[i+j], xr[j]);
        }
        const float xnorm = ((xr[0]+xr[1])+(xr[2]+xr[3])) + ((xr[4]+xr[5])+(xr[6]+xr[7]));

        float d[2]; int cand[2] = {fbi, fsi};
#pragma unroll
        for (int cidx = 0; cidx < 2; ++cidx) {
            const float4* crow = (const float4*)(cb + cand[cidx] * C_DIM);
            float dot = 0.f;
#pragma unroll
            for (int i = 0; i < 16; ++i) {
                float4 f = crow[i];
                dot = fmaf(x[4*i+0], f.x, dot);
                dot = fmaf(x[4*i+1], f.y, dot);
                dot = fmaf(x[4*i+2], f.z, dot);
                dot = fmaf(x[4*i+3], f.w, dot);
            }
            d[cidx] = fmaf(-2.f, dot, xnorm) + wsCn[cand[cidx]];
        }
        int win = (d[1] < d[0] || (d[1] == d[0] && cand[1] < cand[0])) ? cand[1] : cand[0];
        sIdxF[t] = win;
        out[CODES_ELEMS + n_g] = (float)win;
    }
    __syncthreads();

    // ---- codes write: out[b][c][hw] = cb[idx][c], coalesced over hw
    {
        const int c_hi = t >> 6, nl = t & 63;
        const int idx = sIdxF[nl];
        const int n_g = base_n + nl;
        const int bb = n_g >> 10, hwv = n_g & 1023;
#pragma unroll
        for (int j = 0; j < 8; ++j) {
            const int c = c_hi * 8 + j;
            out[bb * CHW + c * HW + hwv] = cb[idx * C_DIM + c];
        }
    }
}

extern "C" void kernel_launch(void* const* d_in, const int* in_sizes, int n_in,
                              void* d_out, int out_size, void* d_ws, size_t ws_size,
                              hipStream_t stream) {
    const float* z  = (const float*)d_in[0];
    const float* cb = (const float*)d_in[1];
    float* out = (float*)d_out;
    half8* wsA  = (half8*)d_ws;
    float* wsCn = (float*)((char*)d_ws + WS_A_ELEMS * sizeof(half8));

    prep_kernel<<<33, 256, 0, stream>>>(cb, wsA, wsCn);
    vq_kernel<<<N_TOTAL / NBLK, THREADS, 0, stream>>>(z, cb, wsA, wsCn, out);
}

// Round 7
// 91.979 us; speedup vs baseline: 1.8602x; 1.0000x over previous
//
#include <hip/hip_runtime.h>

// z: [32,64,32,32] fp32, codebook: [1024,64] fp32
#define C_DIM   64
#define K_CODES 1024
#define HW      1024
#define CHW     (C_DIM * HW)             // 65536
#define N_TOTAL 32768
#define CODES_ELEMS 2097152

#define THREADS 512                      // 8 waves: ktl = w&3 (k-split), nt = w>>2 (n-tile)
#define NBLK    64
#define NGROUPS 8

typedef _Float16 half8  __attribute__((ext_vector_type(8)));
typedef float    f32x16 __attribute__((ext_vector_type(16)));

#define WS_A_ELEMS 16384                 // half8 count: 256 KB A-frags

__device__ __forceinline__ bool better(float k1, int i1, float k2, int i2) {
    return (k1 > k2) || (k1 == k2 && i1 < i2);
}
__device__ __forceinline__ void merge2(float& bk, int& bi, float& sk, int& si,
                                       float obk, int obi, float osk, int osi) {
    if (better(obk, obi, bk, bi)) {
        float nsk; int nsi;
        if (better(bk, bi, osk, osi)) { nsk = bk; nsi = bi; } else { nsk = osk; nsi = osi; }
        bk = obk; bi = obi; sk = nsk; si = nsi;
    } else {
        if (better(obk, obi, sk, si)) { sk = obk; si = obi; }
    }
}

// One-shot prep: blocks 0..31 -> hi/lo fp16 A-fragment layout; block 32 -> cnorm.
__global__ void prep_kernel(const float* __restrict__ cb, half8* __restrict__ wsA,
                            float* __restrict__ wsCn) {
    if (blockIdx.x < 32) {
        const int tid = blockIdx.x * 256 + threadIdx.x;   // 0..8191
        const int kt = tid >> 8, q = (tid >> 6) & 3, l = tid & 63;
        const int k  = kt * 32 + (l & 31);
        const int c0 = q * 16 + (l >> 5) * 8;
        const float4* p = (const float4*)(cb + k * C_DIM + c0);
        float4 f0 = p[0], f1 = p[1];
        float v[8] = {f0.x,f0.y,f0.z,f0.w,f1.x,f1.y,f1.z,f1.w};
        half8 h8, l8;
#pragma unroll
        for (int j = 0; j < 8; ++j) {
            _Float16 hh = (_Float16)v[j];
            _Float16 ll = (_Float16)(v[j] - (float)hh);
            h8[j] = hh; l8[j] = ll;
        }
        wsA[((kt * 4 + q) * 2 + 0) * 64 + l] = h8;
        wsA[((kt * 4 + q) * 2 + 1) * 64 + l] = l8;
    } else {
#pragma unroll
        for (int rep = 0; rep < 4; ++rep) {
            const int k = threadIdx.x * 4 + rep;
            const float4* row = (const float4*)(cb + k * C_DIM);
            float r[8];
            {
                float4 f0 = row[0], f1 = row[1];
                float v[8] = {f0.x,f0.y,f0.z,f0.w,f1.x,f1.y,f1.z,f1.w};
#pragma unroll
                for (int j = 0; j < 8; ++j) r[j] = v[j]*v[j];
            }
#pragma unroll
            for (int i = 2; i < 16; i += 2) {
                float4 f0 = row[i], f1 = row[i+1];
                float v[8] = {f0.x,f0.y,f0.z,f0.w,f1.x,f1.y,f1.z,f1.w};
#pragma unroll
                for (int j = 0; j < 8; ++j) r[j] = fmaf(v[j], v[j], r[j]);
            }
            wsCn[k] = ((r[0]+r[1])+(r[2]+r[3])) + ((r[4]+r[5])+(r[6]+r[7]));
        }
    }
}

__launch_bounds__(THREADS, 4)
__global__ void vq_kernel(const float* __restrict__ z, const float* __restrict__ cb,
                          const half8* __restrict__ wsA, const float* __restrict__ wsCn,
                          float* __restrict__ out) {
    __shared__ half8 sStage[1024];                 // 16 KB: B-frags
    __shared__ float sRed[2][4][32][4];
    __shared__ int   sIdxF[NBLK];

    const int t    = threadIdx.x;
    const int lane = t & 63;
    const int w    = t >> 6;
    const int ktl  = w & 3;
    const int nt   = w >> 2;
    const int base_n = blockIdx.x * NBLK;

    // ---- Stage B-fragments (x -> fp16 hi/lo) ----
    {
        const int nt_s = t >> 8, q = (t >> 6) & 3, l = t & 63;
        const int n_g = base_n + nt_s * 32 + (l & 31);
        const int bb = n_g >> 10, hwv = n_g & 1023;
        const int c0 = q * 16 + (l >> 5) * 8;
        half8 h8, l8;
#pragma unroll
        for (int j = 0; j < 8; ++j) {
            float v = z[bb * CHW + (c0 + j) * HW + hwv];
            _Float16 hh = (_Float16)v;
            _Float16 ll = (_Float16)(v - (float)hh);
            h8[j] = hh; l8[j] = ll;
        }
        sStage[((nt_s * 4 + q) * 2 + 0) * 64 + l] = h8;
        sStage[((nt_s * 4 + q) * 2 + 1) * 64 + l] = l8;
    }
    __syncthreads();

    half8 b_xh[4], b_xl[4];
#pragma unroll
    for (int q = 0; q < 4; ++q) {
        b_xh[q] = sStage[((nt * 4 + q) * 2 + 0) * 64 + lane];
        b_xl[q] = sStage[((nt * 4 + q) * 2 + 1) * 64 + lane];
    }
    half8 b_one = {};
    if (lane < 32) { b_one[0] = (_Float16)1.0f; b_one[1] = (_Float16)1.0f; }

    // ---- k-group loop, software-pipelined: MFMA(g) -> issue loads(g+1) -> scan(g).
    // Two persistent top-2 chains (r 0-7 / 8-15) shorten the compare dep chain;
    // merged once after the loop with index tiebreak (first-occurrence preserved).
    float bk0 = -3.4e38f, sk0 = -3.4e38f; int bi0 = 0, si0 = 0;
    float bk1 = -3.4e38f, sk1 = -3.4e38f; int bi1 = 0, si1 = 0;

    half8 a_h[4], a_l[4];
    float cn_cur;
    {
        const int kt = ktl;                        // g = 0
#pragma unroll
        for (int q = 0; q < 4; ++q) {
            a_h[q] = wsA[((kt * 4 + q) * 2 + 0) * 64 + lane];
            a_l[q] = wsA[((kt * 4 + q) * 2 + 1) * 64 + lane];
        }
        cn_cur = wsCn[kt * 32 + (lane & 31)];
    }

#pragma unroll
    for (int g = 0; g < NGROUPS; ++g) {
        const int kt = g * 4 + ktl;
        half8 a_cn = {};
        {
            float cn2 = -0.5f * cn_cur;
            _Float16 hh = (_Float16)cn2;
            _Float16 ll = (_Float16)(cn2 - (float)hh);
            if (lane < 32) { a_cn[0] = hh; a_cn[1] = ll; }
        }

        f32x16 acc = {};
#pragma unroll
        for (int q = 0; q < 4; ++q) acc = __builtin_amdgcn_mfma_f32_32x32x16_f16(a_h[q], b_xh[q], acc, 0, 0, 0);
#pragma unroll
        for (int q = 0; q < 4; ++q) acc = __builtin_amdgcn_mfma_f32_32x32x16_f16(a_l[q], b_xh[q], acc, 0, 0, 0);
#pragma unroll
        for (int q = 0; q < 4; ++q) acc = __builtin_amdgcn_mfma_f32_32x32x16_f16(a_h[q], b_xl[q], acc, 0, 0, 0);
        acc = __builtin_amdgcn_mfma_f32_32x32x16_f16(a_cn, b_one, acc, 0, 0, 0);

        // prefetch next group's A-frags while we scan this accumulator
        if (g + 1 < NGROUPS) {
            const int ktn = (g + 1) * 4 + ktl;
#pragma unroll
            for (int q = 0; q < 4; ++q) {
                a_h[q] = wsA[((ktn * 4 + q) * 2 + 0) * 64 + lane];
                a_l[q] = wsA[((ktn * 4 + q) * 2 + 1) * 64 + lane];
            }
            cn_cur = wsCn[ktn * 32 + (lane & 31)];
        }

        const int kbase = kt * 32 + 4 * (lane >> 5);
#pragma unroll
        for (int r = 0; r < 8; ++r) {
            float v = acc[r];
            int ki = kbase + (r & 3) + 8 * (r >> 2);
            if (v > bk0)      { sk0 = bk0; si0 = bi0; bk0 = v; bi0 = ki; }
            else if (v > sk0) { sk0 = v; si0 = ki; }
        }
#pragma unroll
        for (int r = 8; r < 16; ++r) {
            float v = acc[r];
            int ki = kbase + (r & 3) + 8 * (r >> 2);
            if (v > bk1)      { sk1 = bk1; si1 = bi1; bk1 = v; bi1 = ki; }
            else if (v > sk1) { sk1 = v; si1 = ki; }
        }
    }

    // merge the two chains, then lane halves
    float bk = bk0, sk = sk0; int bi = bi0, si = si0;
    merge2(bk, bi, sk, si, bk1, bi1, sk1, si1);
    {
        float obk = __shfl_xor(bk, 32, 64); int obi = __shfl_xor(bi, 32, 64);
        float osk = __shfl_xor(sk, 32, 64); int osi = __shfl_xor(si, 32, 64);
        merge2(bk, bi, sk, si, obk, obi, osk, osi);
    }
    if (lane < 32) {
        sRed[nt][ktl][lane][0] = bk;
        sRed[nt][ktl][lane][1] = __int_as_float(bi);
        sRed[nt][ktl][lane][2] = sk;
        sRed[nt][ktl][lane][3] = __int_as_float(si);
    }
    __syncthreads();

    // ---- per-n final merge + exact fp32 top-2 refinement ----
    if (t < NBLK) {
        const int ntf = t >> 5, col = t & 31;
        float fbk = sRed[ntf][0][col][0]; int fbi = __float_as_int(sRed[ntf][0][col][1]);
        float fsk = sRed[ntf][0][col][2]; int fsi = __float_as_int(sRed[ntf][0][col][3]);
#pragma unroll
        for (int p = 1; p < 4; ++p)
            merge2(fbk, fbi, fsk, fsi,
                   sRed[ntf][p][col][0], __float_as_int(sRed[ntf][p][col][1]),
                   sRed[ntf][p][col][2], __float_as_int(sRed[ntf][p][col][3]));

        const int n_g = base_n + t;
        const int bb = n_g >> 10, hwv = n_g & 1023;
        const float* zp = z + bb * CHW + hwv;
        float x[C_DIM];
#pragma unroll
        for (int c = 0; c < C_DIM; ++c) x[c] = zp[c * HW];
        float xr[8];
#pragma unroll
        for (int j = 0; j < 8; ++j) xr[j] = x[j] * x[j];
#pragma unroll
        for (int i = 8; i < 64; i += 8) {
#pragma unroll
            for (int j = 0; j < 8; ++j) xr[j] = fmaf(x[i+j], x[i+j], xr[j]);
        }
        const float xnorm = ((xr[0]+xr[1])+(xr[2]+xr[3])) + ((xr[4]+xr[5])+(xr[6]+xr[7]));

        float d[2]; int cand[2] = {fbi, fsi};
#pragma unroll
        for (int cidx = 0; cidx < 2; ++cidx) {
            const float4* crow = (const float4*)(cb + cand[cidx] * C_DIM);
            float dot = 0.f;
#pragma unroll
            for (int i = 0; i < 16; ++i) {
                float4 f = crow[i];
                dot = fmaf(x[4*i+0], f.x, dot);
                dot = fmaf(x[4*i+1], f.y, dot);
                dot = fmaf(x[4*i+2], f.z, dot);
                dot = fmaf(x[4*i+3], f.w, dot);
            }
            d[cidx] = fmaf(-2.f, dot, xnorm) + wsCn[cand[cidx]];
        }
        int win = (d[1] < d[0] || (d[1] == d[0] && cand[1] < cand[0])) ? cand[1] : cand[0];
        sIdxF[t] = win;
        out[CODES_ELEMS + n_g] = (float)win;
    }
    __syncthreads();

    // ---- codes write ----
    {
        const int c_hi = t >> 6, nl = t & 63;
        const int idx = sIdxF[nl];
        const int n_g = base_n + nl;
        const int bb = n_g >> 10, hwv = n_g & 1023;
#pragma unroll
        for (int j = 0; j < 8; ++j) {
            const int c = c_hi * 8 + j;
            out[bb * CHW + c * HW + hwv] = cb[idx * C_DIM + c];
        }
    }
}

extern "C" void kernel_launch(void* const* d_in, const int* in_sizes, int n_in,
                              void* d_out, int out_size, void* d_ws, size_t ws_size,
                              hipStream_t stream) {
    const float* z  = (const float*)d_in[0];
    const float* cb = (const float*)d_in[1];
    float* out = (float*)d_out;
    half8* wsA  = (half8*)d_ws;
    float* wsCn = (float*)((char*)d_ws + WS_A_ELEMS * sizeof(half8));

    prep_kernel<<<33, 256, 0, stream>>>(cb, wsA, wsCn);
    vq_kernel<<<N_TOTAL / NBLK, THREADS, 0, stream>>>(z, cb, wsA, wsCn, out);
}